// Round 15
// baseline (241.433 us; speedup 1.0000x reference)
//
#include <hip/hip_runtime.h>
#include <hip/hip_bf16.h>

// Problem constants
#define Bn 4
#define Hn 512
#define Wn 512
#define Cn 16
#define Sn 10
#define HWn (Hn*Wn)          // 262144 = 1<<18
#define BHW (Bn*HWn)         // 1048576
#define NG (BHW/4)           // pixel-groups for conv0 (4 px/thread)

// Load 6 consecutive row floats (w0-1 .. w0+4) with boundary zeros. (conv0 only)
__device__ __forceinline__ void load_row6(const float* __restrict__ rp, bool valid,
                                          int w0, float* r) {
    if (valid) {
        float4 v = *reinterpret_cast<const float4*>(rp + w0);
        r[1] = v.x; r[2] = v.y; r[3] = v.z; r[4] = v.w;
        r[0] = (w0 > 0)   ? rp[w0 - 1] : 0.f;
        r[5] = (w0 < 508) ? rp[w0 + 4] : 0.f;
    } else {
        r[0] = r[1] = r[2] = r[3] = r[4] = r[5] = 0.f;
    }
}

// ---------------- conv0: 1->16, 3x3, pad 1, bias; 4 px/thread ----------------
__global__ __launch_bounds__(256) void k_conv0(const float* __restrict__ photos,
        const float* __restrict__ w0v, const float* __restrict__ b0,
        float* __restrict__ out) {
    __shared__ float wp[Cn*12];
    __shared__ float sb[Cn];
    int t = threadIdx.x;
    if (t < Cn*9) { int o = t / 9, k = t % 9; wp[o*12 + k] = w0v[t]; }
    if (t < Cn) sb[t] = b0[t];
    __syncthreads();
    int idx = blockIdx.x * 256 + t;
    int w0 = (idx & 127) << 2, h = (idx >> 7) & 511, b = idx >> 16;
    const float* pb = photos + (b << 18);
    float xr[3][6];
    #pragma unroll
    for (int dy = 0; dy < 3; ++dy) {
        int hh = h + dy - 1;
        load_row6(pb + (hh << 9), (unsigned)hh < 512u, w0, xr[dy]);
    }
    #pragma unroll
    for (int o = 0; o < Cn; ++o) {
        float4 wa = *(const float4*)&wp[o*12];
        float4 wb = *(const float4*)&wp[o*12 + 4];
        float wk8 = wp[o*12 + 8];
        float wk[9] = {wa.x, wa.y, wa.z, wa.w, wb.x, wb.y, wb.z, wb.w, wk8};
        float bv = sb[o];
        float a0 = bv, a1 = bv, a2 = bv, a3 = bv;
        #pragma unroll
        for (int dy = 0; dy < 3; ++dy)
            #pragma unroll
            for (int dx = 0; dx < 3; ++dx) {
                float wv = wk[dy*3 + dx];
                a0 += xr[dy][dx + 0] * wv;
                a1 += xr[dy][dx + 1] * wv;
                a2 += xr[dy][dx + 2] * wv;
                a3 += xr[dy][dx + 3] * wv;
            }
        float4 r; r.x = a0; r.y = a1; r.z = a2; r.w = a3;
        *reinterpret_cast<float4*>(out + ((b*Cn + o) << 18) + (h << 9) + w0) = r;
    }
}

// ====================== LDS-tiled staged conv kernels ======================
// Tile: 128 w x 8 h outputs per block, 256 threads; tw=t&31 (4 px), th=t>>5.
// TWO channels staged per phase (8 barriers/block), double-buffered.
// Weights via wave-uniform scalar loads (constant cache) — no weight LDS.

struct StageRegs { float4 b0, b1; float hl, hr; };

__device__ __forceinline__ StageRegs stage_load(const float* __restrict__ xc,
                                                int w0, int h0, int t) {
    StageRegs r;
    {
        int row = t >> 5, c4 = t & 31;
        int gh = h0 - 1 + row;
        r.b0 = make_float4(0.f, 0.f, 0.f, 0.f);
        if ((unsigned)gh < 512u)
            r.b0 = *reinterpret_cast<const float4*>(xc + (gh << 9) + w0 + (c4 << 2));
    }
    r.b1 = make_float4(0.f, 0.f, 0.f, 0.f);
    if (t < 64) {
        int s = t + 256;
        int row = s >> 5, c4 = s & 31;
        int gh = h0 - 1 + row;
        if ((unsigned)gh < 512u)
            r.b1 = *reinterpret_cast<const float4*>(xc + (gh << 9) + w0 + (c4 << 2));
    }
    r.hl = 0.f; r.hr = 0.f;
    if (t < 10) {
        int gh = h0 - 1 + t;
        if (w0 > 0 && (unsigned)gh < 512u) r.hl = xc[(gh << 9) + w0 - 1];
    }
    if (t >= 32 && t < 42) {
        int gh = h0 - 1 + (t - 32);
        if (w0 + 128 < 512 && (unsigned)gh < 512u) r.hr = xc[(gh << 9) + w0 + 128];
    }
    return r;
}

__device__ __forceinline__ void stage_write(float (*tile)[128], float* hL, float* hR,
                                            const StageRegs& r, int t) {
    *reinterpret_cast<float4*>(&tile[t >> 5][(t & 31) << 2]) = r.b0;
    if (t < 64) {
        int s = t + 256;
        *reinterpret_cast<float4*>(&tile[s >> 5][(s & 31) << 2]) = r.b1;
    }
    if (t < 10) hL[t] = r.hl;
    if (t >= 32 && t < 42) hR[t - 32] = r.hr;
}

#define READ_ROWS(tilebuf, hLbuf, hRbuf)                                        \
    float4 v_[3]; float lft_[3], rgt_[3];                                       \
    _Pragma("unroll")                                                           \
    for (int dy = 0; dy < 3; ++dy) {                                            \
        v_[dy] = *reinterpret_cast<const float4*>(&(tilebuf)[th + dy][tw << 2]);\
        float l_ = __shfl_up(v_[dy].w, 1);                                      \
        if (tw == 0) l_ = (hLbuf)[th + dy];                                     \
        float rr_ = __shfl_down(v_[dy].x, 1);                                   \
        if (tw == 31) rr_ = (hRbuf)[th + dy];                                   \
        lft_[dy] = l_; rgt_[dy] = rr_;                                          \
    }

// ------ inverted residual (dw3x3+bn+relu6+pw1x1+bn+skip), staged 2ch/phase ------
__global__ __launch_bounds__(256) void k_ir(const float* __restrict__ x,
        float* __restrict__ y, const float* __restrict__ dww,
        const float* __restrict__ as_, const float* __restrict__ ab_,
        const float* __restrict__ pww, const float* __restrict__ bs_,
        const float* __restrict__ bb_) {
    __shared__ float tile[2][2][10][128];
    __shared__ float hLs[2][2][10], hRs[2][2][10];
    int t = threadIdx.x;

    int bx = blockIdx.x;
    int wt = bx & 3, ht = (bx >> 2) & 63, b = bx >> 8;
    int w0 = wt << 7, h0 = ht << 3;
    int tw = t & 31, th = t >> 5;
    const float* xb = x + ((size_t)b << 22);

    float acc[Cn][4];
    #pragma unroll
    for (int o = 0; o < Cn; ++o) { acc[o][0] = acc[o][1] = acc[o][2] = acc[o][3] = 0.f; }

    {
        StageRegs s0 = stage_load(xb, w0, h0, t);
        StageRegs s1 = stage_load(xb + (1 << 18), w0, h0, t);
        stage_write(tile[0][0], hLs[0][0], hRs[0][0], s0, t);
        stage_write(tile[0][1], hLs[0][1], hRs[0][1], s1, t);
    }
    __syncthreads();

    #pragma unroll 1
    for (int g = 0; g < 8; ++g) {
        StageRegs n0, n1;
        bool more = (g + 1 < 8);
        if (more) {
            n0 = stage_load(xb + (((g + 1) * 2 + 0) << 18), w0, h0, t);
            n1 = stage_load(xb + (((g + 1) * 2 + 1) << 18), w0, h0, t);
        }
        int bf = g & 1;
        #pragma unroll
        for (int j = 0; j < 2; ++j) {
            int cc = g * 2 + j;
            READ_ROWS(tile[bf][j], hLs[bf][j], hRs[bf][j]);
            // depthwise weights: wave-uniform scalar loads (constant cache)
            float wk[9];
            #pragma unroll
            for (int k = 0; k < 9; ++k) wk[k] = dww[cc*9 + k];
            float t0 = 0.f, t1 = 0.f, t2 = 0.f, t3 = 0.f;
            #pragma unroll
            for (int dy = 0; dy < 3; ++dy) {
                float r6[6] = {lft_[dy], v_[dy].x, v_[dy].y, v_[dy].z, v_[dy].w, rgt_[dy]};
                #pragma unroll
                for (int dx = 0; dx < 3; ++dx) {
                    float wv = wk[dy*3 + dx];
                    t0 += r6[dx + 0] * wv;
                    t1 += r6[dx + 1] * wv;
                    t2 += r6[dx + 2] * wv;
                    t3 += r6[dx + 3] * wv;
                }
            }
            float sc = as_[cc], sh = ab_[cc];
            t0 = fminf(fmaxf(t0*sc + sh, 0.f), 6.f);
            t1 = fminf(fmaxf(t1*sc + sh, 0.f), 6.f);
            t2 = fminf(fmaxf(t2*sc + sh, 0.f), 6.f);
            t3 = fminf(fmaxf(t3*sc + sh, 0.f), 6.f);
            // pointwise: wave-uniform scalar loads
            #pragma unroll
            for (int o = 0; o < Cn; ++o) {
                float wq = pww[o*Cn + cc];
                acc[o][0] += t0*wq; acc[o][1] += t1*wq;
                acc[o][2] += t2*wq; acc[o][3] += t3*wq;
            }
        }
        if (more) {
            int nb = (g + 1) & 1;
            stage_write(tile[nb][0], hLs[nb][0], hRs[nb][0], n0, t);
            stage_write(tile[nb][1], hLs[nb][1], hRs[nb][1], n1, t);
            __syncthreads();
        }
    }
    int h = h0 + th, wg = w0 + (tw << 2);
    #pragma unroll
    for (int o = 0; o < Cn; ++o) {
        const float* xo = xb + (o << 18) + (h << 9) + wg;
        float4 xv = *(const float4*)xo;   // L2-hot residual re-read
        float sc = bs_[o], sh = bb_[o];
        float4 r;
        r.x = xv.x + acc[o][0]*sc + sh;
        r.y = xv.y + acc[o][1]*sc + sh;
        r.z = xv.z + acc[o][2]*sc + sh;
        r.w = xv.w + acc[o][3]*sc + sh;
        *reinterpret_cast<float4*>(y + ((size_t)b << 22) + (o << 18) + (h << 9) + wg) = r;
    }
}

// ------ score conv 16->10, staged 2ch/phase; weights scalar; stats fused ------
__global__ __launch_bounds__(256) void k_convs(const float* __restrict__ x,
        const float* __restrict__ wsw, const float* __restrict__ bsv,
        float* __restrict__ s, float2* __restrict__ part) {
    __shared__ float tile[2][2][10][128];
    __shared__ float hLs[2][2][10], hRs[2][2][10];
    __shared__ float wsum[4][Sn], wsq[4][Sn];
    int t = threadIdx.x;

    int bx = blockIdx.x;
    int wt = bx & 3, ht = (bx >> 2) & 63, b = bx >> 8;
    int w0 = wt << 7, h0 = ht << 3;
    int tw = t & 31, th = t >> 5;
    const float* xb = x + ((size_t)b << 22);

    float acc[Sn][4];
    #pragma unroll
    for (int o = 0; o < Sn; ++o) {
        float bv = bsv[o];
        acc[o][0] = bv; acc[o][1] = bv; acc[o][2] = bv; acc[o][3] = bv;
    }

    {
        StageRegs s0 = stage_load(xb, w0, h0, t);
        StageRegs s1 = stage_load(xb + (1 << 18), w0, h0, t);
        stage_write(tile[0][0], hLs[0][0], hRs[0][0], s0, t);
        stage_write(tile[0][1], hLs[0][1], hRs[0][1], s1, t);
    }
    __syncthreads();

    #pragma unroll 1
    for (int g = 0; g < 8; ++g) {
        StageRegs n0, n1;
        bool more = (g + 1 < 8);
        if (more) {
            n0 = stage_load(xb + (((g + 1) * 2 + 0) << 18), w0, h0, t);
            n1 = stage_load(xb + (((g + 1) * 2 + 1) << 18), w0, h0, t);
        }
        int bf = g & 1;
        #pragma unroll
        for (int j = 0; j < 2; ++j) {
            int cc = g * 2 + j;
            READ_ROWS(tile[bf][j], hLs[bf][j], hRs[bf][j]);
            #pragma unroll
            for (int o = 0; o < Sn; ++o) {
                const float* wb_ = wsw + (o*Cn + cc)*9;   // wave-uniform scalar
                float wk[9];
                #pragma unroll
                for (int k = 0; k < 9; ++k) wk[k] = wb_[k];
                #pragma unroll
                for (int dy = 0; dy < 3; ++dy) {
                    float r6[6] = {lft_[dy], v_[dy].x, v_[dy].y, v_[dy].z, v_[dy].w, rgt_[dy]};
                    #pragma unroll
                    for (int dx = 0; dx < 3; ++dx) {
                        float wv = wk[dy*3 + dx];
                        acc[o][0] += r6[dx + 0] * wv;
                        acc[o][1] += r6[dx + 1] * wv;
                        acc[o][2] += r6[dx + 2] * wv;
                        acc[o][3] += r6[dx + 3] * wv;
                    }
                }
            }
        }
        if (more) {
            int nb = (g + 1) & 1;
            stage_write(tile[nb][0], hLs[nb][0], hRs[nb][0], n0, t);
            stage_write(tile[nb][1], hLs[nb][1], hRs[nb][1], n1, t);
            __syncthreads();
        }
    }
    int h = h0 + th, wg = w0 + (tw << 2);
    #pragma unroll
    for (int o = 0; o < Sn; ++o) {
        float4 r; r.x = acc[o][0]; r.y = acc[o][1]; r.z = acc[o][2]; r.w = acc[o][3];
        *reinterpret_cast<float4*>(s + ((b*Sn + o) << 18) + (h << 9) + wg) = r;
    }
    // ---- fused instance-norm partial sums (float shuffles) ----
    int lane = t & 63, wid = t >> 6;
    #pragma unroll
    for (int o = 0; o < Sn; ++o) {
        float sm = acc[o][0] + acc[o][1] + acc[o][2] + acc[o][3];
        float qq = acc[o][0]*acc[o][0] + acc[o][1]*acc[o][1]
                 + acc[o][2]*acc[o][2] + acc[o][3]*acc[o][3];
        #pragma unroll
        for (int off = 32; off > 0; off >>= 1) {
            sm += __shfl_xor(sm, off);
            qq += __shfl_xor(qq, off);
        }
        if (lane == 0) { wsum[wid][o] = sm; wsq[wid][o] = qq; }
    }
    __syncthreads();
    if (t < Sn) {
        float sm = wsum[0][t] + wsum[1][t] + wsum[2][t] + wsum[3][t];
        float qq = wsq[0][t] + wsq[1][t] + wsq[2][t] + wsq[3][t];
        int blk = bx & 255;                        // 256 blocks per batch image
        float2 p; p.x = sm; p.y = qq;
        part[((b * Sn + t) << 8) + blk] = p;
    }
}

// ---------------- instance norm finalize: reduce 256 block-partials ----------
__global__ __launch_bounds__(256) void k_in_fin(const float2* __restrict__ part,
                                                float2* __restrict__ stats) {
    __shared__ double ss[256], qq[256];
    int bc = blockIdx.x;
    int t = threadIdx.x;
    float2 p = part[(bc << 8) + t];
    ss[t] = (double)p.x;
    qq[t] = (double)p.y;
    __syncthreads();
    for (int off = 128; off > 0; off >>= 1) {
        if (t < off) { ss[t] += ss[t + off]; qq[t] += qq[t + off]; }
        __syncthreads();
    }
    if (t == 0) {
        double mu = ss[0] / (double)HWn;
        double var = qq[0] / (double)HWn - mu * mu;
        float2 st; st.x = (float)mu; st.y = rsqrtf((float)var + 1e-5f);
        stats[bc] = st;
    }
}

// norm + leaky-relu applied on the fly (S stays raw everywhere)
__device__ __forceinline__ float nrm(float v, float2 st) {
    float r = (v - st.x) * st.y;
    return r >= 0.f ? r : 0.01f * r;
}

// ---- R1: chanmax + rowmax. One block per (b,h) row; 2 px/thread. ----
__global__ __launch_bounds__(256) void k_chan_rowmax(const float* __restrict__ s,
        const float2* __restrict__ stats, float* __restrict__ m1) {
    __shared__ float rowbuf[512];
    int bh = blockIdx.x;
    int b = bh >> 9, h = bh & 511;
    int t = threadIdx.x, w0 = t << 1;
    const float* sp = s + ((size_t)(b * Sn) << 18) + (h << 9) + w0;
    float mx0 = -INFINITY, mx1 = -INFINITY;
    #pragma unroll
    for (int c = 0; c < Sn; ++c) {
        float2 st = stats[b * Sn + c];
        float2 v = *reinterpret_cast<const float2*>(sp + ((size_t)c << 18));
        mx0 = fmaxf(mx0, nrm(v.x, st));
        mx1 = fmaxf(mx1, nrm(v.y, st));
    }
    rowbuf[w0] = mx0; rowbuf[w0 + 1] = mx1;
    __syncthreads();
    float2 o;
    {
        int lo = max(w0 - 7, 0), hi = min(w0 + 7, 511);
        float m = -INFINITY;
        for (int ww = lo; ww <= hi; ++ww) m = fmaxf(m, rowbuf[ww]);
        o.x = m;
        int w1 = w0 + 1;
        lo = max(w1 - 7, 0); hi = min(w1 + 7, 511);
        m = -INFINITY;
        for (int ww = lo; ww <= hi; ++ww) m = fmaxf(m, rowbuf[ww]);
        o.y = m;
    }
    *reinterpret_cast<float2*>(m1 + (bh << 9) + w0) = o;
}

// ---- R2: colmax -> M, expsum, rowsum -> T. One block per (b,h) row. ----
__global__ __launch_bounds__(256) void k_col_expsum(const float* __restrict__ s,
        const float2* __restrict__ stats, const float* __restrict__ m1,
        float* __restrict__ mfull, float* __restrict__ tout) {
    __shared__ float esbuf[512];
    int bh = blockIdx.x;
    int b = bh >> 9, h = bh & 511;
    int t = threadIdx.x, w0 = t << 1;
    int lo = max(h - 7, 0), hi = min(h + 7, 511);
    float2 m = make_float2(-INFINITY, -INFINITY);
    for (int hh = lo; hh <= hi; ++hh) {
        float2 v = *reinterpret_cast<const float2*>(m1 + ((size_t)b << 18) + (hh << 9) + w0);
        m.x = fmaxf(m.x, v.x); m.y = fmaxf(m.y, v.y);
    }
    *reinterpret_cast<float2*>(mfull + (bh << 9) + w0) = m;
    const float* sp = s + ((size_t)(b * Sn) << 18) + (h << 9) + w0;
    float es0 = 0.f, es1 = 0.f;
    #pragma unroll
    for (int c = 0; c < Sn; ++c) {
        float2 st = stats[b * Sn + c];
        float2 v = *reinterpret_cast<const float2*>(sp + ((size_t)c << 18));
        es0 += __expf(7.f * (nrm(v.x, st) - m.x));
        es1 += __expf(7.f * (nrm(v.y, st) - m.y));
    }
    esbuf[w0] = es0; esbuf[w0 + 1] = es1;
    __syncthreads();
    float2 o;
    {
        int wlo = max(w0 - 7, 0), whi = min(w0 + 7, 511);
        float a = 0.f;
        for (int ww = wlo; ww <= whi; ++ww) a += esbuf[ww];
        o.x = a;
        int w1 = w0 + 1;
        wlo = max(w1 - 7, 0); whi = min(w1 + 7, 511);
        a = 0.f;
        for (int ww = wlo; ww <= whi; ++ww) a += esbuf[ww];
        o.y = a;
    }
    *reinterpret_cast<float2*>(tout + (bh << 9) + w0) = o;
}

// ---- R3: colsum -> SU, channel softmax, outputs. One block per (b,h) row. ----
__global__ __launch_bounds__(256) void k_final(const float* __restrict__ s,
        const float2* __restrict__ stats, const float* __restrict__ mfull,
        const float* __restrict__ tin, const float* __restrict__ scl,
        float* __restrict__ out) {
    __shared__ float sscale[Sn];
    int t = threadIdx.x;
    if (t < Sn) sscale[t] = scl[t];
    __syncthreads();
    int bh = blockIdx.x;
    int b = bh >> 9, h = bh & 511;
    int w0 = t << 1;
    int lo = max(h - 7, 0), hi = min(h + 7, 511);
    float2 su = make_float2(0.f, 0.f);
    for (int hh = lo; hh <= hi; ++hh) {
        float2 v = *reinterpret_cast<const float2*>(tin + ((size_t)b << 18) + (hh << 9) + w0);
        su.x += v.x; su.y += v.y;
    }
    float2 m = *reinterpret_cast<const float2*>(mfull + (bh << 9) + w0);
    float d0 = 1.f / (su.x + 1e-8f), d1i = 1.f / (su.y + 1e-8f);
    const float* sp = s + ((size_t)(b * Sn) << 18) + (h << 9) + w0;
    float pr0[Sn], pr1[Sn];
    float mx0 = -INFINITY, mx1 = -INFINITY;
    #pragma unroll
    for (int c = 0; c < Sn; ++c) {
        float2 st = stats[b * Sn + c];
        float2 v = *reinterpret_cast<const float2*>(sp + ((size_t)c << 18));
        float p0 = expf(7.f * (nrm(v.x, st) - m.x)) * d0;
        float p1 = expf(7.f * (nrm(v.y, st) - m.y)) * d1i;
        pr0[c] = p0; pr1[c] = p1;
        mx0 = fmaxf(mx0, p0); mx1 = fmaxf(mx1, p1);
    }
    float e0[Sn], e1[Sn];
    float s0 = 0.f, s1 = 0.f;
    #pragma unroll
    for (int c = 0; c < Sn; ++c) {
        e0[c] = expf(100.f * (pr0[c] - mx0)); s0 += e0[c];
        e1[c] = expf(100.f * (pr1[c] - mx1)); s1 += e1[c];
    }
    float i0 = 1.f / (s0 + 1e-8f), i1 = 1.f / (s1 + 1e-8f);
    float sc0 = 0.f, sc1 = 0.f, sl0 = 0.f, sl1 = 0.f;
    #pragma unroll
    for (int c = 0; c < Sn; ++c) {
        float p0 = e0[c] * i0, p1 = e1[c] * i1;
        sc0 += pr0[c] * p0; sl0 += sscale[c] * p0;
        sc1 += pr1[c] * p1; sl1 += sscale[c] * p1;
    }
    int oi = (bh << 9) + w0;
    float2 r0; r0.x = sc0; r0.y = sc1;
    float2 r1; r1.x = sl0; r1.y = sl1;
    *reinterpret_cast<float2*>(out + oi) = r0;
    *reinterpret_cast<float2*>(out + BHW + oi) = r1;
}

extern "C" void kernel_launch(void* const* d_in, const int* in_sizes, int n_in,
                              void* d_out, int out_size, void* d_ws, size_t ws_size,
                              hipStream_t stream) {
    const float* photos = (const float*)d_in[0];
    const float* w0     = (const float*)d_in[1];
    const float* b0     = (const float*)d_in[2];
    const float* dw1_w  = (const float*)d_in[3];
    const float* bn1a_s = (const float*)d_in[4];
    const float* bn1a_b = (const float*)d_in[5];
    const float* pw1_w  = (const float*)d_in[6];
    const float* bn1b_s = (const float*)d_in[7];
    const float* bn1b_b = (const float*)d_in[8];
    const float* dw2_w  = (const float*)d_in[9];
    const float* bn2a_s = (const float*)d_in[10];
    const float* bn2a_b = (const float*)d_in[11];
    const float* pw2_w  = (const float*)d_in[12];
    const float* bn2b_s = (const float*)d_in[13];
    const float* bn2b_b = (const float*)d_in[14];
    const float* ws_w   = (const float*)d_in[15];
    const float* bs_v   = (const float*)d_in[16];
    const float* scl    = (const float*)d_in[17];

    char* wsb = (char*)d_ws;
    float* A  = (float*)(wsb);                         // 64 MiB (B,16,H,W)
    float* Bb = (float*)(wsb + 67108864);              // 64 MiB (B,16,H,W)
    float* S  = (float*)(wsb + 134217728);             // 40 MiB raw conv output
    // Launch order: conv0->A; ir1 A->Bb; ir2 Bb->A; convs A->S(+part).
    float2* stats = (float2*)Bb;                       // 40 float2
    float2* part  = (float2*)(Bb + 1024);              // 40*256 float2 (80 KB)
    float* M1 = A;
    float* M  = A + 1 * (1 << 20);
    float* T  = A + 2 * (1 << 20);

    dim3 blk(256);
    int gNG   = NG / 256;             // 1024 blocks (conv0, 4 px/thread)
    int gTILE = 4 * 64 * Bn;          // 1024 tile blocks (128x8 per block)
    int gROW  = Bn * Hn;              // 2048 row-blocks

    k_conv0<<<gNG, blk, 0, stream>>>(photos, w0, b0, A);
    k_ir<<<gTILE, blk, 0, stream>>>(A, Bb, dw1_w, bn1a_s, bn1a_b, pw1_w, bn1b_s, bn1b_b);
    k_ir<<<gTILE, blk, 0, stream>>>(Bb, A, dw2_w, bn2a_s, bn2a_b, pw2_w, bn2b_s, bn2b_b);
    k_convs<<<gTILE, blk, 0, stream>>>(A, ws_w, bs_v, S, part);
    k_in_fin<<<Bn * Sn, blk, 0, stream>>>(part, stats);
    k_chan_rowmax<<<gROW, blk, 0, stream>>>(S, stats, M1);
    k_col_expsum<<<gROW, blk, 0, stream>>>(S, stats, M1, M, T);
    k_final<<<gROW, blk, 0, stream>>>(S, stats, M, T, scl, (float*)d_out);
}

// Round 16
// 191.900 us; speedup vs baseline: 1.2581x; 1.2581x over previous
//
#include <hip/hip_runtime.h>
#include <hip/hip_bf16.h>

// Problem constants
#define Bn 4
#define Hn 512
#define Wn 512
#define Cn 16
#define Sn 10
#define HWn (Hn*Wn)          // 262144 = 1<<18
#define BHW (Bn*HWn)         // 1048576
#define NG (BHW/4)           // pixel-groups for conv0 (4 px/thread)

// Load 6 consecutive row floats (w0-1 .. w0+4) with boundary zeros. (conv0 only)
__device__ __forceinline__ void load_row6(const float* __restrict__ rp, bool valid,
                                          int w0, float* r) {
    if (valid) {
        float4 v = *reinterpret_cast<const float4*>(rp + w0);
        r[1] = v.x; r[2] = v.y; r[3] = v.z; r[4] = v.w;
        r[0] = (w0 > 0)   ? rp[w0 - 1] : 0.f;
        r[5] = (w0 < 508) ? rp[w0 + 4] : 0.f;
    } else {
        r[0] = r[1] = r[2] = r[3] = r[4] = r[5] = 0.f;
    }
}

// ---------------- conv0: 1->16, 3x3, pad 1, bias; 4 px/thread ----------------
__global__ __launch_bounds__(256) void k_conv0(const float* __restrict__ photos,
        const float* __restrict__ w0v, const float* __restrict__ b0,
        float* __restrict__ out) {
    __shared__ float wp[Cn*12];
    __shared__ float sb[Cn];
    int t = threadIdx.x;
    if (t < Cn*9) { int o = t / 9, k = t % 9; wp[o*12 + k] = w0v[t]; }
    if (t < Cn) sb[t] = b0[t];
    __syncthreads();
    int idx = blockIdx.x * 256 + t;
    int w0 = (idx & 127) << 2, h = (idx >> 7) & 511, b = idx >> 16;
    const float* pb = photos + (b << 18);
    float xr[3][6];
    #pragma unroll
    for (int dy = 0; dy < 3; ++dy) {
        int hh = h + dy - 1;
        load_row6(pb + (hh << 9), (unsigned)hh < 512u, w0, xr[dy]);
    }
    #pragma unroll
    for (int o = 0; o < Cn; ++o) {
        float4 wa = *(const float4*)&wp[o*12];
        float4 wb = *(const float4*)&wp[o*12 + 4];
        float wk8 = wp[o*12 + 8];
        float wk[9] = {wa.x, wa.y, wa.z, wa.w, wb.x, wb.y, wb.z, wb.w, wk8};
        float bv = sb[o];
        float a0 = bv, a1 = bv, a2 = bv, a3 = bv;
        #pragma unroll
        for (int dy = 0; dy < 3; ++dy)
            #pragma unroll
            for (int dx = 0; dx < 3; ++dx) {
                float wv = wk[dy*3 + dx];
                a0 += xr[dy][dx + 0] * wv;
                a1 += xr[dy][dx + 1] * wv;
                a2 += xr[dy][dx + 2] * wv;
                a3 += xr[dy][dx + 3] * wv;
            }
        float4 r; r.x = a0; r.y = a1; r.z = a2; r.w = a3;
        *reinterpret_cast<float4*>(out + ((b*Cn + o) << 18) + (h << 9) + w0) = r;
    }
}

// ====================== LDS-tiled staged conv kernels (round-14 final) ======
// Tile: 128 w x 8 h outputs per block, 256 threads; tw=t&31 (4 px), th=t>>5.
// Per channel: stage 10x128 body + 2x10 halo cols, double-buffered, 1 sync/ch.
// Weights via wave-uniform scalar loads (constant cache) — no weight LDS.

struct StageRegs { float4 b0, b1; float hl, hr; };

__device__ __forceinline__ StageRegs stage_load(const float* __restrict__ xc,
                                                int w0, int h0, int t) {
    StageRegs r;
    {
        int row = t >> 5, c4 = t & 31;
        int gh = h0 - 1 + row;
        r.b0 = make_float4(0.f, 0.f, 0.f, 0.f);
        if ((unsigned)gh < 512u)
            r.b0 = *reinterpret_cast<const float4*>(xc + (gh << 9) + w0 + (c4 << 2));
    }
    r.b1 = make_float4(0.f, 0.f, 0.f, 0.f);
    if (t < 64) {
        int s = t + 256;
        int row = s >> 5, c4 = s & 31;
        int gh = h0 - 1 + row;
        if ((unsigned)gh < 512u)
            r.b1 = *reinterpret_cast<const float4*>(xc + (gh << 9) + w0 + (c4 << 2));
    }
    r.hl = 0.f; r.hr = 0.f;
    if (t < 10) {
        int gh = h0 - 1 + t;
        if (w0 > 0 && (unsigned)gh < 512u) r.hl = xc[(gh << 9) + w0 - 1];
    }
    if (t >= 32 && t < 42) {
        int gh = h0 - 1 + (t - 32);
        if (w0 + 128 < 512 && (unsigned)gh < 512u) r.hr = xc[(gh << 9) + w0 + 128];
    }
    return r;
}

__device__ __forceinline__ void stage_write(float (*tile)[128], float* hL, float* hR,
                                            const StageRegs& r, int t) {
    *reinterpret_cast<float4*>(&tile[t >> 5][(t & 31) << 2]) = r.b0;
    if (t < 64) {
        int s = t + 256;
        *reinterpret_cast<float4*>(&tile[s >> 5][(s & 31) << 2]) = r.b1;
    }
    if (t < 10) hL[t] = r.hl;
    if (t >= 32 && t < 42) hR[t - 32] = r.hr;
}

#define READ_ROWS(tilebuf, hLbuf, hRbuf)                                        \
    float4 v_[3]; float lft_[3], rgt_[3];                                       \
    _Pragma("unroll")                                                           \
    for (int dy = 0; dy < 3; ++dy) {                                            \
        v_[dy] = *reinterpret_cast<const float4*>(&(tilebuf)[th + dy][tw << 2]);\
        float l_ = __shfl_up(v_[dy].w, 1);                                      \
        if (tw == 0) l_ = (hLbuf)[th + dy];                                     \
        float rr_ = __shfl_down(v_[dy].x, 1);                                   \
        if (tw == 31) rr_ = (hRbuf)[th + dy];                                   \
        lft_[dy] = l_; rgt_[dy] = rr_;                                          \
    }

// ------ inverted residual (dw3x3+bn+relu6+pw1x1+bn+skip), staged ------
__global__ __launch_bounds__(256) void k_ir(const float* __restrict__ x,
        float* __restrict__ y, const float* __restrict__ dww,
        const float* __restrict__ as_, const float* __restrict__ ab_,
        const float* __restrict__ pww, const float* __restrict__ bs_,
        const float* __restrict__ bb_) {
    __shared__ float tile[2][10][128];
    __shared__ float hLs[2][10], hRs[2][10];
    int t = threadIdx.x;

    int bx = blockIdx.x;
    int wt = bx & 3, ht = (bx >> 2) & 63, b = bx >> 8;
    int w0 = wt << 7, h0 = ht << 3;
    int tw = t & 31, th = t >> 5;
    const float* xb = x + ((size_t)b << 22);

    float acc[Cn][4];
    #pragma unroll
    for (int o = 0; o < Cn; ++o) { acc[o][0] = acc[o][1] = acc[o][2] = acc[o][3] = 0.f; }

    StageRegs sr = stage_load(xb, w0, h0, t);
    stage_write(tile[0], hLs[0], hRs[0], sr, t);
    __syncthreads();

    #pragma unroll 1
    for (int c = 0; c < Cn; ++c) {
        if (c + 1 < Cn) sr = stage_load(xb + ((c + 1) << 18), w0, h0, t);
        int bf = c & 1;
        READ_ROWS(tile[bf], hLs[bf], hRs[bf]);
        // depthwise weights: wave-uniform scalar loads (constant cache)
        float wk[9];
        #pragma unroll
        for (int k = 0; k < 9; ++k) wk[k] = dww[c*9 + k];
        float t0 = 0.f, t1 = 0.f, t2 = 0.f, t3 = 0.f;
        #pragma unroll
        for (int dy = 0; dy < 3; ++dy) {
            float r6[6] = {lft_[dy], v_[dy].x, v_[dy].y, v_[dy].z, v_[dy].w, rgt_[dy]};
            #pragma unroll
            for (int dx = 0; dx < 3; ++dx) {
                float wv = wk[dy*3 + dx];
                t0 += r6[dx + 0] * wv;
                t1 += r6[dx + 1] * wv;
                t2 += r6[dx + 2] * wv;
                t3 += r6[dx + 3] * wv;
            }
        }
        float sc = as_[c], sh = ab_[c];
        t0 = fminf(fmaxf(t0*sc + sh, 0.f), 6.f);
        t1 = fminf(fmaxf(t1*sc + sh, 0.f), 6.f);
        t2 = fminf(fmaxf(t2*sc + sh, 0.f), 6.f);
        t3 = fminf(fmaxf(t3*sc + sh, 0.f), 6.f);
        // pointwise: pww[o*Cn + c], wave-uniform scalar loads
        #pragma unroll
        for (int o = 0; o < Cn; ++o) {
            float wq = pww[o*Cn + c];
            acc[o][0] += t0*wq; acc[o][1] += t1*wq;
            acc[o][2] += t2*wq; acc[o][3] += t3*wq;
        }
        if (c + 1 < Cn) {
            int nb = (c + 1) & 1;
            stage_write(tile[nb], hLs[nb], hRs[nb], sr, t);
            __syncthreads();
        }
    }
    int h = h0 + th, wg = w0 + (tw << 2);
    #pragma unroll
    for (int o = 0; o < Cn; ++o) {
        const float* xo = xb + (o << 18) + (h << 9) + wg;
        float4 xv = *(const float4*)xo;   // L2-hot residual re-read
        float sc = bs_[o], sh = bb_[o];
        float4 r;
        r.x = xv.x + acc[o][0]*sc + sh;
        r.y = xv.y + acc[o][1]*sc + sh;
        r.z = xv.z + acc[o][2]*sc + sh;
        r.w = xv.w + acc[o][3]*sc + sh;
        *reinterpret_cast<float4*>(y + ((size_t)b << 22) + (o << 18) + (h << 9) + wg) = r;
    }
}

// ------ score conv 16->10, staged; weights scalar; stats partials fused ------
__global__ __launch_bounds__(256) void k_convs(const float* __restrict__ x,
        const float* __restrict__ wsw, const float* __restrict__ bsv,
        float* __restrict__ s, float2* __restrict__ part) {
    __shared__ float tile[2][10][128];
    __shared__ float hLs[2][10], hRs[2][10];
    __shared__ float wsum[4][Sn], wsq[4][Sn];
    int t = threadIdx.x;

    int bx = blockIdx.x;
    int wt = bx & 3, ht = (bx >> 2) & 63, b = bx >> 8;
    int w0 = wt << 7, h0 = ht << 3;
    int tw = t & 31, th = t >> 5;
    const float* xb = x + ((size_t)b << 22);

    float acc[Sn][4];
    #pragma unroll
    for (int o = 0; o < Sn; ++o) {
        float bv = bsv[o];
        acc[o][0] = bv; acc[o][1] = bv; acc[o][2] = bv; acc[o][3] = bv;
    }

    StageRegs sr = stage_load(xb, w0, h0, t);
    stage_write(tile[0], hLs[0], hRs[0], sr, t);
    __syncthreads();

    #pragma unroll 1
    for (int c = 0; c < Cn; ++c) {
        if (c + 1 < Cn) sr = stage_load(xb + ((c + 1) << 18), w0, h0, t);
        int bf = c & 1;
        READ_ROWS(tile[bf], hLs[bf], hRs[bf]);
        #pragma unroll
        for (int o = 0; o < Sn; ++o) {
            // weights: wave-uniform scalar loads (original o-major layout)
            const float* wb_ = wsw + (o*Cn + c)*9;
            float wk[9];
            #pragma unroll
            for (int k = 0; k < 9; ++k) wk[k] = wb_[k];
            #pragma unroll
            for (int dy = 0; dy < 3; ++dy) {
                float r6[6] = {lft_[dy], v_[dy].x, v_[dy].y, v_[dy].z, v_[dy].w, rgt_[dy]};
                #pragma unroll
                for (int dx = 0; dx < 3; ++dx) {
                    float wv = wk[dy*3 + dx];
                    acc[o][0] += r6[dx + 0] * wv;
                    acc[o][1] += r6[dx + 1] * wv;
                    acc[o][2] += r6[dx + 2] * wv;
                    acc[o][3] += r6[dx + 3] * wv;
                }
            }
        }
        if (c + 1 < Cn) {
            int nb = (c + 1) & 1;
            stage_write(tile[nb], hLs[nb], hRs[nb], sr, t);
            __syncthreads();
        }
    }
    int h = h0 + th, wg = w0 + (tw << 2);
    #pragma unroll
    for (int o = 0; o < Sn; ++o) {
        float4 r; r.x = acc[o][0]; r.y = acc[o][1]; r.z = acc[o][2]; r.w = acc[o][3];
        *reinterpret_cast<float4*>(s + ((b*Sn + o) << 18) + (h << 9) + wg) = r;
    }
    // ---- fused instance-norm partial sums (float shuffles) ----
    int lane = t & 63, wid = t >> 6;
    #pragma unroll
    for (int o = 0; o < Sn; ++o) {
        float sm = acc[o][0] + acc[o][1] + acc[o][2] + acc[o][3];
        float qq = acc[o][0]*acc[o][0] + acc[o][1]*acc[o][1]
                 + acc[o][2]*acc[o][2] + acc[o][3]*acc[o][3];
        #pragma unroll
        for (int off = 32; off > 0; off >>= 1) {
            sm += __shfl_xor(sm, off);
            qq += __shfl_xor(qq, off);
        }
        if (lane == 0) { wsum[wid][o] = sm; wsq[wid][o] = qq; }
    }
    __syncthreads();
    if (t < Sn) {
        float sm = wsum[0][t] + wsum[1][t] + wsum[2][t] + wsum[3][t];
        float qq = wsq[0][t] + wsq[1][t] + wsq[2][t] + wsq[3][t];
        int blk = bx & 255;                        // 256 blocks per batch image
        float2 p; p.x = sm; p.y = qq;
        part[((b * Sn + t) << 8) + blk] = p;
    }
}

// ---------------- instance norm finalize: reduce 256 block-partials ----------
__global__ __launch_bounds__(256) void k_in_fin(const float2* __restrict__ part,
                                                float2* __restrict__ stats) {
    __shared__ double ss[256], qq[256];
    int bc = blockIdx.x;
    int t = threadIdx.x;
    float2 p = part[(bc << 8) + t];
    ss[t] = (double)p.x;
    qq[t] = (double)p.y;
    __syncthreads();
    for (int off = 128; off > 0; off >>= 1) {
        if (t < off) { ss[t] += ss[t + off]; qq[t] += qq[t + off]; }
        __syncthreads();
    }
    if (t == 0) {
        double mu = ss[0] / (double)HWn;
        double var = qq[0] / (double)HWn - mu * mu;
        float2 st; st.x = (float)mu; st.y = rsqrtf((float)var + 1e-5f);
        stats[bc] = st;
    }
}

// norm + leaky-relu applied on the fly (S stays raw everywhere)
__device__ __forceinline__ float nrm(float v, float2 st) {
    float r = (v - st.x) * st.y;
    return r >= 0.f ? r : 0.01f * r;
}

// ---- R1: chanmax + rowmax. One block per (b,h) row; 2 px/thread. ----
__global__ __launch_bounds__(256) void k_chan_rowmax(const float* __restrict__ s,
        const float2* __restrict__ stats, float* __restrict__ m1) {
    __shared__ float rowbuf[512];
    int bh = blockIdx.x;
    int b = bh >> 9, h = bh & 511;
    int t = threadIdx.x, w0 = t << 1;
    const float* sp = s + ((size_t)(b * Sn) << 18) + (h << 9) + w0;
    float mx0 = -INFINITY, mx1 = -INFINITY;
    #pragma unroll
    for (int c = 0; c < Sn; ++c) {
        float2 st = stats[b * Sn + c];
        float2 v = *reinterpret_cast<const float2*>(sp + ((size_t)c << 18));
        mx0 = fmaxf(mx0, nrm(v.x, st));
        mx1 = fmaxf(mx1, nrm(v.y, st));
    }
    rowbuf[w0] = mx0; rowbuf[w0 + 1] = mx1;
    __syncthreads();
    float2 o;
    {
        int lo = max(w0 - 7, 0), hi = min(w0 + 7, 511);
        float m = -INFINITY;
        for (int ww = lo; ww <= hi; ++ww) m = fmaxf(m, rowbuf[ww]);
        o.x = m;
        int w1 = w0 + 1;
        lo = max(w1 - 7, 0); hi = min(w1 + 7, 511);
        m = -INFINITY;
        for (int ww = lo; ww <= hi; ++ww) m = fmaxf(m, rowbuf[ww]);
        o.y = m;
    }
    *reinterpret_cast<float2*>(m1 + (bh << 9) + w0) = o;
}

// ---- R2: colmax -> M, expsum, rowsum -> T. One block per (b,h) row. ----
__global__ __launch_bounds__(256) void k_col_expsum(const float* __restrict__ s,
        const float2* __restrict__ stats, const float* __restrict__ m1,
        float* __restrict__ mfull, float* __restrict__ tout) {
    __shared__ float esbuf[512];
    int bh = blockIdx.x;
    int b = bh >> 9, h = bh & 511;
    int t = threadIdx.x, w0 = t << 1;
    int lo = max(h - 7, 0), hi = min(h + 7, 511);
    float2 m = make_float2(-INFINITY, -INFINITY);
    for (int hh = lo; hh <= hi; ++hh) {
        float2 v = *reinterpret_cast<const float2*>(m1 + ((size_t)b << 18) + (hh << 9) + w0);
        m.x = fmaxf(m.x, v.x); m.y = fmaxf(m.y, v.y);
    }
    *reinterpret_cast<float2*>(mfull + (bh << 9) + w0) = m;
    const float* sp = s + ((size_t)(b * Sn) << 18) + (h << 9) + w0;
    float es0 = 0.f, es1 = 0.f;
    #pragma unroll
    for (int c = 0; c < Sn; ++c) {
        float2 st = stats[b * Sn + c];
        float2 v = *reinterpret_cast<const float2*>(sp + ((size_t)c << 18));
        es0 += __expf(7.f * (nrm(v.x, st) - m.x));
        es1 += __expf(7.f * (nrm(v.y, st) - m.y));
    }
    esbuf[w0] = es0; esbuf[w0 + 1] = es1;
    __syncthreads();
    float2 o;
    {
        int wlo = max(w0 - 7, 0), whi = min(w0 + 7, 511);
        float a = 0.f;
        for (int ww = wlo; ww <= whi; ++ww) a += esbuf[ww];
        o.x = a;
        int w1 = w0 + 1;
        wlo = max(w1 - 7, 0); whi = min(w1 + 7, 511);
        a = 0.f;
        for (int ww = wlo; ww <= whi; ++ww) a += esbuf[ww];
        o.y = a;
    }
    *reinterpret_cast<float2*>(tout + (bh << 9) + w0) = o;
}

// ---- R3: colsum -> SU, channel softmax, outputs. One block per (b,h) row. ----
__global__ __launch_bounds__(256) void k_final(const float* __restrict__ s,
        const float2* __restrict__ stats, const float* __restrict__ mfull,
        const float* __restrict__ tin, const float* __restrict__ scl,
        float* __restrict__ out) {
    __shared__ float sscale[Sn];
    int t = threadIdx.x;
    if (t < Sn) sscale[t] = scl[t];
    __syncthreads();
    int bh = blockIdx.x;
    int b = bh >> 9, h = bh & 511;
    int w0 = t << 1;
    int lo = max(h - 7, 0), hi = min(h + 7, 511);
    float2 su = make_float2(0.f, 0.f);
    for (int hh = lo; hh <= hi; ++hh) {
        float2 v = *reinterpret_cast<const float2*>(tin + ((size_t)b << 18) + (hh << 9) + w0);
        su.x += v.x; su.y += v.y;
    }
    float2 m = *reinterpret_cast<const float2*>(mfull + (bh << 9) + w0);
    float d0 = 1.f / (su.x + 1e-8f), d1i = 1.f / (su.y + 1e-8f);
    const float* sp = s + ((size_t)(b * Sn) << 18) + (h << 9) + w0;
    float pr0[Sn], pr1[Sn];
    float mx0 = -INFINITY, mx1 = -INFINITY;
    #pragma unroll
    for (int c = 0; c < Sn; ++c) {
        float2 st = stats[b * Sn + c];
        float2 v = *reinterpret_cast<const float2*>(sp + ((size_t)c << 18));
        float p0 = expf(7.f * (nrm(v.x, st) - m.x)) * d0;
        float p1 = expf(7.f * (nrm(v.y, st) - m.y)) * d1i;
        pr0[c] = p0; pr1[c] = p1;
        mx0 = fmaxf(mx0, p0); mx1 = fmaxf(mx1, p1);
    }
    float e0[Sn], e1[Sn];
    float s0 = 0.f, s1 = 0.f;
    #pragma unroll
    for (int c = 0; c < Sn; ++c) {
        e0[c] = expf(100.f * (pr0[c] - mx0)); s0 += e0[c];
        e1[c] = expf(100.f * (pr1[c] - mx1)); s1 += e1[c];
    }
    float i0 = 1.f / (s0 + 1e-8f), i1 = 1.f / (s1 + 1e-8f);
    float sc0 = 0.f, sc1 = 0.f, sl0 = 0.f, sl1 = 0.f;
    #pragma unroll
    for (int c = 0; c < Sn; ++c) {
        float p0 = e0[c] * i0, p1 = e1[c] * i1;
        sc0 += pr0[c] * p0; sl0 += sscale[c] * p0;
        sc1 += pr1[c] * p1; sl1 += sscale[c] * p1;
    }
    int oi = (bh << 9) + w0;
    float2 r0; r0.x = sc0; r0.y = sc1;
    float2 r1; r1.x = sl0; r1.y = sl1;
    *reinterpret_cast<float2*>(out + oi) = r0;
    *reinterpret_cast<float2*>(out + BHW + oi) = r1;
}

extern "C" void kernel_launch(void* const* d_in, const int* in_sizes, int n_in,
                              void* d_out, int out_size, void* d_ws, size_t ws_size,
                              hipStream_t stream) {
    const float* photos = (const float*)d_in[0];
    const float* w0     = (const float*)d_in[1];
    const float* b0     = (const float*)d_in[2];
    const float* dw1_w  = (const float*)d_in[3];
    const float* bn1a_s = (const float*)d_in[4];
    const float* bn1a_b = (const float*)d_in[5];
    const float* pw1_w  = (const float*)d_in[6];
    const float* bn1b_s = (const float*)d_in[7];
    const float* bn1b_b = (const float*)d_in[8];
    const float* dw2_w  = (const float*)d_in[9];
    const float* bn2a_s = (const float*)d_in[10];
    const float* bn2a_b = (const float*)d_in[11];
    const float* pw2_w  = (const float*)d_in[12];
    const float* bn2b_s = (const float*)d_in[13];
    const float* bn2b_b = (const float*)d_in[14];
    const float* ws_w   = (const float*)d_in[15];
    const float* bs_v   = (const float*)d_in[16];
    const float* scl    = (const float*)d_in[17];

    char* wsb = (char*)d_ws;
    float* A  = (float*)(wsb);                         // 64 MiB (B,16,H,W)
    float* Bb = (float*)(wsb + 67108864);              // 64 MiB (B,16,H,W)
    float* S  = (float*)(wsb + 134217728);             // 40 MiB raw conv output
    // Launch order: conv0->A; ir1 A->Bb; ir2 Bb->A; convs A->S(+part).
    float2* stats = (float2*)Bb;                       // 40 float2
    float2* part  = (float2*)(Bb + 1024);              // 40*256 float2 (80 KB)
    float* M1 = A;
    float* M  = A + 1 * (1 << 20);
    float* T  = A + 2 * (1 << 20);

    dim3 blk(256);
    int gNG   = NG / 256;             // 1024 blocks (conv0, 4 px/thread)
    int gTILE = 4 * 64 * Bn;          // 1024 tile blocks (128x8 per block)
    int gROW  = Bn * Hn;              // 2048 row-blocks

    k_conv0<<<gNG, blk, 0, stream>>>(photos, w0, b0, A);
    k_ir<<<gTILE, blk, 0, stream>>>(A, Bb, dw1_w, bn1a_s, bn1a_b, pw1_w, bn1b_s, bn1b_b);
    k_ir<<<gTILE, blk, 0, stream>>>(Bb, A, dw2_w, bn2a_s, bn2a_b, pw2_w, bn2b_s, bn2b_b);
    k_convs<<<gTILE, blk, 0, stream>>>(A, ws_w, bs_v, S, part);
    k_in_fin<<<Bn * Sn, blk, 0, stream>>>(part, stats);
    k_chan_rowmax<<<gROW, blk, 0, stream>>>(S, stats, M1);
    k_col_expsum<<<gROW, blk, 0, stream>>>(S, stats, M1, M, T);
    k_final<<<gROW, blk, 0, stream>>>(S, stats, M, T, scl, (float*)d_out);
}